// Round 1
// baseline (918.159 us; speedup 1.0000x reference)
//
#include <hip/hip_runtime.h>
#include <hip/hip_bf16.h>

// Problem constants
#define L_  4
#define G_  20000
#define C_  128
#define E_  320000
#define KD_ 16
#define LC_ 512            // L_*C_
#define DECAY_ 0.5f
#define LN_EPS_ 1e-5f

// ---------------------------------------------------------------------------
// Per-row weight contribution: w_row = sum_kd (x.Wk[:,kd]) * (x.Wq[:,kd])
// One wave (64 lanes) holds the 128-float row as float2 per lane.
// Strategy: reduce Q[kd] fully across lanes (16x6 shuffles), then each lane
// dots its K-partials with the full Q and we reduce that scalar (6 shuffles).
// Returns the full sum (valid in all lanes). Caller divides by KD.
// ---------------------------------------------------------------------------
__device__ __forceinline__ float row_weight(float2 xv, int lane,
                                            const float* __restrict__ Wk,
                                            const float* __restrict__ Wq) {
    const int c0 = lane * 2, c1 = c0 + 1;
    float wk0[16], wk1[16], wq0[16], wq1[16];
#pragma unroll
    for (int kd = 0; kd < 16; ++kd) {
        wk0[kd] = Wk[c0 * 16 + kd];
        wk1[kd] = Wk[c1 * 16 + kd];
        wq0[kd] = Wq[c0 * 16 + kd];
        wq1[kd] = Wq[c1 * 16 + kd];
    }
    float kp[16], qp[16];
#pragma unroll
    for (int kd = 0; kd < 16; ++kd) {
        kp[kd] = xv.x * wk0[kd] + xv.y * wk1[kd];
        qp[kd] = xv.x * wq0[kd] + xv.y * wq1[kd];
    }
    // full reduction of Q partials across the 64 lanes
#pragma unroll
    for (int kd = 0; kd < 16; ++kd) {
#pragma unroll
        for (int m = 1; m < 64; m <<= 1) qp[kd] += __shfl_xor(qp[kd], m);
    }
    float s = 0.f;
#pragma unroll
    for (int kd = 0; kd < 16; ++kd) s += kp[kd] * qp[kd];
#pragma unroll
    for (int m = 1; m < 64; m <<= 1) s += __shfl_xor(s, m);
    return s;
}

// ---------------------------------------------------------------------------
// init: cur0[g][l*128+c] = x[l][g][c]; weights[g*4+l] = mean_kd(k*q)
// grid = G_ blocks, 256 threads (4 waves = 4 l-rows per g)
// ---------------------------------------------------------------------------
__global__ void init_kernel(const float* __restrict__ x,
                            const float* __restrict__ Wk,
                            const float* __restrict__ Wq,
                            float* __restrict__ cur0,
                            float* __restrict__ weights) {
    const int g = blockIdx.x;
    const int wid = threadIdx.x >> 6;
    const int lane = threadIdx.x & 63;
    const int l = wid;

    const float2* xp = (const float2*)(x + ((size_t)l * G_ + g) * C_);
    float2 xv = xp[lane];
    float2* cp = (float2*)(cur0 + (size_t)g * LC_ + l * C_);
    cp[lane] = xv;

    float w = row_weight(xv, lane, Wk, Wq);
    if (lane == 0) weights[g * 4 + l] = w * (1.0f / 16.0f);
}

// ---------------------------------------------------------------------------
// weights iteration: weights[g*4+l] += mean_kd(ck*cq) from cur rows
// ---------------------------------------------------------------------------
__global__ void witer_kernel(const float* __restrict__ cur,
                             const float* __restrict__ Wk,
                             const float* __restrict__ Wq,
                             float* __restrict__ weights) {
    const int g = blockIdx.x;
    const int wid = threadIdx.x >> 6;
    const int lane = threadIdx.x & 63;
    const int l = wid;

    const float2* rp = (const float2*)(cur + (size_t)g * LC_ + l * C_);
    float2 xv = rp[lane];
    float w = row_weight(xv, lane, Wk, Wq);
    if (lane == 0) weights[g * 4 + l] += w * (1.0f / 16.0f);
}

// ---------------------------------------------------------------------------
// CSR build
// ---------------------------------------------------------------------------
__global__ void hist_kernel(const int* __restrict__ row, int* __restrict__ counts) {
    int e = blockIdx.x * 256 + threadIdx.x;
    if (e < E_) atomicAdd(&counts[row[e]], 1);
}

// single-block exclusive scan, 1024 threads
__global__ void scan_kernel(const int* __restrict__ counts,
                            int* __restrict__ offsets, int n) {
    __shared__ int wsum[16];
    const int tid = threadIdx.x;
    const int lane = tid & 63, wid = tid >> 6;
    int carry = 0;
    for (int base = 0; base < n; base += 1024) {
        int i = base + tid;
        int v = (i < n) ? counts[i] : 0;
        int incl = v;
#pragma unroll
        for (int d = 1; d < 64; d <<= 1) {
            int o = __shfl_up(incl, d);
            if (lane >= d) incl += o;
        }
        if (lane == 63) wsum[wid] = incl;
        __syncthreads();
        if (tid < 16) {
            int w = wsum[tid];
#pragma unroll
            for (int d = 1; d < 16; d <<= 1) {
                int o = __shfl_up(w, d);
                if ((tid & 15) >= d) w += o;
            }
            wsum[tid] = w;
        }
        __syncthreads();
        int waveoff = (wid == 0) ? 0 : wsum[wid - 1];
        int excl = carry + waveoff + incl - v;
        if (i < n) offsets[i] = excl;
        carry += wsum[15];
        __syncthreads();   // all reads of wsum done before next chunk overwrites
    }
    if (tid == 0) offsets[n] = carry;
}

__global__ void scatter_kernel(const int* __restrict__ row,
                               const int* __restrict__ col,
                               const float* __restrict__ vals,
                               int* __restrict__ cursor,
                               int* __restrict__ pcol,
                               float* __restrict__ pval) {
    int e = blockIdx.x * 256 + threadIdx.x;
    if (e < E_) {
        int r = row[e];
        int pos = atomicAdd(&cursor[r], 1);
        pcol[pos] = col[e];
        pval[pos] = vals[e] * DECAY_;   // fold DECAY into edge value
    }
}

// ---------------------------------------------------------------------------
// SpMM: cur_out[g] = sum_{edges of g} (val*DECAY) * cur_in[col]
// block = 128 threads (float4 each -> 512 cols), grid = G_
// ---------------------------------------------------------------------------
__global__ void spmm_kernel(const float* __restrict__ cur_in,
                            float* __restrict__ cur_out,
                            const int* __restrict__ offs,
                            const int* __restrict__ pcol,
                            const float* __restrict__ pval) {
    const int g = blockIdx.x;
    const int c4 = threadIdx.x * 4;
    const int s = offs[g], e = offs[g + 1];
    float4 acc = {0.f, 0.f, 0.f, 0.f};
    int i = s;
    for (; i + 2 <= e; i += 2) {
        int col0 = pcol[i], col1 = pcol[i + 1];
        float v0 = pval[i], v1 = pval[i + 1];
        float4 a = *(const float4*)(cur_in + (size_t)col0 * LC_ + c4);
        float4 b = *(const float4*)(cur_in + (size_t)col1 * LC_ + c4);
        acc.x += v0 * a.x + v1 * b.x;
        acc.y += v0 * a.y + v1 * b.y;
        acc.z += v0 * a.z + v1 * b.z;
        acc.w += v0 * a.w + v1 * b.w;
    }
    if (i < e) {
        int col0 = pcol[i];
        float v0 = pval[i];
        float4 a = *(const float4*)(cur_in + (size_t)col0 * LC_ + c4);
        acc.x += v0 * a.x;
        acc.y += v0 * a.y;
        acc.z += v0 * a.z;
        acc.w += v0 * a.w;
    }
    *(float4*)(cur_out + (size_t)g * LC_ + c4) = acc;
}

// ---------------------------------------------------------------------------
// final: acc = cur0+cur1+cur2 (LDS), v = (acc @ Wv) * weights, LayerNorm, out
// block = 128 threads (thread t: l=t>>5, 4 outputs), grid = G_
// ---------------------------------------------------------------------------
__global__ void final_kernel(const float* __restrict__ cur0,
                             const float* __restrict__ cur1,
                             const float* __restrict__ cur2,
                             const float* __restrict__ weights,
                             const float* __restrict__ Wv,
                             const float* __restrict__ gamma,
                             const float* __restrict__ beta,
                             float* __restrict__ out) {
    const int g = blockIdx.x;
    const int t = threadIdx.x;
    __shared__ float la[LC_];

#pragma unroll
    for (int l = 0; l < 4; ++l) {
        int idx = l * C_ + t;
        size_t off = (size_t)g * LC_ + idx;
        la[idx] = cur0[off] + cur1[off] + cur2[off];
    }
    __syncthreads();

    const int l = t >> 5;
    const int c4 = (t & 31) * 4;
    const float* lrow = la + l * C_;
    float4 v = {0.f, 0.f, 0.f, 0.f};
#pragma unroll 8
    for (int c = 0; c < C_; ++c) {
        float a = lrow[c];
        float4 wv = *(const float4*)(Wv + c * C_ + c4);
        v.x += a * wv.x;
        v.y += a * wv.y;
        v.z += a * wv.z;
        v.w += a * wv.w;
    }
    float w = weights[g * 4 + l];
    v.x *= w; v.y *= w; v.z *= w; v.w *= w;

    // LayerNorm over the 128 cols held by this 32-lane group
    float sum = v.x + v.y + v.z + v.w;
#pragma unroll
    for (int m = 1; m < 32; m <<= 1) sum += __shfl_xor(sum, m);
    float mu = sum * (1.0f / 128.0f);
    float4 d = {v.x - mu, v.y - mu, v.z - mu, v.w - mu};
    float ss = d.x * d.x + d.y * d.y + d.z * d.z + d.w * d.w;
#pragma unroll
    for (int m = 1; m < 32; m <<= 1) ss += __shfl_xor(ss, m);
    float var = ss * (1.0f / 128.0f);
    float rs = rsqrtf(var + LN_EPS_);

    float4 gm = *(const float4*)(gamma + c4);
    float4 bt = *(const float4*)(beta + c4);
    float4 o;
    o.x = d.x * rs * gm.x + bt.x;
    o.y = d.y * rs * gm.y + bt.y;
    o.z = d.z * rs * gm.z + bt.z;
    o.w = d.w * rs * gm.w + bt.w;
    *(float4*)(out + ((size_t)l * G_ + g) * C_ + c4) = o;
}

// ---------------------------------------------------------------------------
extern "C" void kernel_launch(void* const* d_in, const int* in_sizes, int n_in,
                              void* d_out, int out_size, void* d_ws, size_t ws_size,
                              hipStream_t stream) {
    const float* x       = (const float*)d_in[0];
    const int*   e_row   = (const int*)d_in[1];
    const int*   e_col   = (const int*)d_in[2];
    const float* e_val   = (const float*)d_in[3];
    const float* Wk      = (const float*)d_in[4];
    const float* Wq      = (const float*)d_in[5];
    const float* Wv      = (const float*)d_in[6];
    const float* gamma   = (const float*)d_in[7];
    const float* beta    = (const float*)d_in[8];
    float* out = (float*)d_out;

    // workspace bump allocator (256B aligned)
    char* p = (char*)d_ws;
    auto alloc = [&](size_t bytes) -> void* {
        void* r = (void*)p;
        p += (bytes + 255) & ~(size_t)255;
        return r;
    };
    float* cur0    = (float*)alloc((size_t)G_ * LC_ * 4);
    float* cur1    = (float*)alloc((size_t)G_ * LC_ * 4);
    float* cur2    = (float*)alloc((size_t)G_ * LC_ * 4);
    float* weights = (float*)alloc((size_t)G_ * L_ * 4);
    int*   counts  = (int*)alloc((size_t)G_ * 4);
    int*   offsets = (int*)alloc((size_t)(G_ + 1) * 4);
    int*   cursor  = (int*)alloc((size_t)G_ * 4);
    int*   pcol    = (int*)alloc((size_t)E_ * 4);
    float* pval    = (float*)alloc((size_t)E_ * 4);

    // CSR build
    hipMemsetAsync(counts, 0, (size_t)G_ * 4, stream);
    hist_kernel<<<(E_ + 255) / 256, 256, 0, stream>>>(e_row, counts);
    scan_kernel<<<1, 1024, 0, stream>>>(counts, offsets, G_);
    hipMemcpyAsync(cursor, offsets, (size_t)G_ * 4, hipMemcpyDeviceToDevice, stream);
    scatter_kernel<<<(E_ + 255) / 256, 256, 0, stream>>>(e_row, e_col, e_val,
                                                         cursor, pcol, pval);

    // transpose + initial weights
    init_kernel<<<G_, 256, 0, stream>>>(x, Wk, Wq, cur0, weights);

    // iteration 1
    spmm_kernel<<<G_, 128, 0, stream>>>(cur0, cur1, offsets, pcol, pval);
    witer_kernel<<<G_, 256, 0, stream>>>(cur1, Wk, Wq, weights);
    // iteration 2
    spmm_kernel<<<G_, 128, 0, stream>>>(cur1, cur2, offsets, pcol, pval);
    witer_kernel<<<G_, 256, 0, stream>>>(cur2, Wk, Wq, weights);

    // values @ Wv, * weights, LayerNorm
    final_kernel<<<G_, 128, 0, stream>>>(cur0, cur1, cur2, weights, Wv,
                                         gamma, beta, out);
}

// Round 6
// 681.664 us; speedup vs baseline: 1.3469x; 1.3469x over previous
//
#include <hip/hip_runtime.h>
#include <hip/hip_bf16.h>

// Problem constants
#define L_  4
#define G_  20000
#define C_  128
#define E_  320000
#define KD_ 16
#define LC_ 512            // L_*C_
#define DECAY_ 0.5f
#define LN_EPS_ 1e-5f
#define NG_ 16             // g's per final block (64 rows)

// ---------------------------------------------------------------------------
// Weight contribution for one l-row held by a 32-lane group as float4/lane.
// cc = channel offset of this lane's 4 channels within the 128-channel row.
// Returns mean_kd( (row@Wk)[kd] * (row@Wq)[kd] ), group-reduced (all lanes).
// ---------------------------------------------------------------------------
__device__ __forceinline__ float weight_contrib(float4 acc, int cc,
                                                const float* __restrict__ Wk,
                                                const float* __restrict__ Wq) {
    float kp[16], qp[16];
#pragma unroll
    for (int i = 0; i < 16; ++i) { kp[i] = 0.f; qp[i] = 0.f; }
    float av[4] = {acc.x, acc.y, acc.z, acc.w};
#pragma unroll
    for (int j = 0; j < 4; ++j) {
        const float4* wkr = (const float4*)(Wk + (size_t)(cc + j) * KD_);
        const float4* wqr = (const float4*)(Wq + (size_t)(cc + j) * KD_);
        float aj = av[j];
#pragma unroll
        for (int q4 = 0; q4 < 4; ++q4) {
            float4 wk = wkr[q4], wq = wqr[q4];
            kp[q4 * 4 + 0] += aj * wk.x; kp[q4 * 4 + 1] += aj * wk.y;
            kp[q4 * 4 + 2] += aj * wk.z; kp[q4 * 4 + 3] += aj * wk.w;
            qp[q4 * 4 + 0] += aj * wq.x; qp[q4 * 4 + 1] += aj * wq.y;
            qp[q4 * 4 + 2] += aj * wq.z; qp[q4 * 4 + 3] += aj * wq.w;
        }
    }
    // reduce q-projection across the 32-lane group (xor masks < 32 stay inside)
#pragma unroll
    for (int i = 0; i < 16; ++i) {
#pragma unroll
        for (int m = 1; m < 32; m <<= 1) qp[i] += __shfl_xor(qp[i], m);
    }
    float s = 0.f;
#pragma unroll
    for (int i = 0; i < 16; ++i) s += kp[i] * qp[i];
#pragma unroll
    for (int m = 1; m < 32; m <<= 1) s += __shfl_xor(s, m);
    return s * (1.0f / 16.0f);
}

// ---------------------------------------------------------------------------
// init: cur0[g][l*128+c] = x[l][g][c]; weights[g*4+l] = mean_kd(k*q)
// 128 threads: l = t>>5, 4 channels per lane
// ---------------------------------------------------------------------------
__global__ __launch_bounds__(128) void init_kernel(
        const float* __restrict__ x,
        const float* __restrict__ Wk,
        const float* __restrict__ Wq,
        float* __restrict__ cur0,
        float* __restrict__ weights) {
    const int g = blockIdx.x;
    const int t = threadIdx.x;
    const int l = t >> 5;
    const int cc = (t & 31) * 4;

    float4 xv = *(const float4*)(x + ((size_t)l * G_ + g) * C_ + cc);
    *(float4*)(cur0 + (size_t)g * LC_ + l * C_ + cc) = xv;

    float w = weight_contrib(xv, cc, Wk, Wq);
    if ((t & 31) == 0) weights[g * 4 + l] = w;
}

// ---------------------------------------------------------------------------
// CSR build
// ---------------------------------------------------------------------------
__global__ void hist_kernel(const int* __restrict__ row, int* __restrict__ counts) {
    int e = blockIdx.x * 256 + threadIdx.x;
    if (e < E_) atomicAdd(&counts[row[e]], 1);
}

// single-block exclusive scan, 1024 threads
__global__ void scan_kernel(const int* __restrict__ counts,
                            int* __restrict__ offsets, int n) {
    __shared__ int wsum[16];
    const int tid = threadIdx.x;
    const int lane = tid & 63, wid = tid >> 6;
    int carry = 0;
    for (int base = 0; base < n; base += 1024) {
        int i = base + tid;
        int v = (i < n) ? counts[i] : 0;
        int incl = v;
#pragma unroll
        for (int d = 1; d < 64; d <<= 1) {
            int o = __shfl_up(incl, d);
            if (lane >= d) incl += o;
        }
        if (lane == 63) wsum[wid] = incl;
        __syncthreads();
        if (tid < 16) {
            int w = wsum[tid];
#pragma unroll
            for (int d = 1; d < 16; d <<= 1) {
                int o = __shfl_up(w, d);
                if ((tid & 15) >= d) w += o;
            }
            wsum[tid] = w;
        }
        __syncthreads();
        int waveoff = (wid == 0) ? 0 : wsum[wid - 1];
        int excl = carry + waveoff + incl - v;
        if (i < n) offsets[i] = excl;
        carry += wsum[15];
        __syncthreads();
    }
    if (tid == 0) offsets[n] = carry;
}

__global__ void scatter_kernel(const int* __restrict__ row,
                               const int* __restrict__ col,
                               const float* __restrict__ vals,
                               int* __restrict__ cursor,
                               int* __restrict__ pcol,
                               float* __restrict__ pval) {
    int e = blockIdx.x * 256 + threadIdx.x;
    if (e < E_) {
        int r = row[e];
        int pos = atomicAdd(&cursor[r], 1);
        pcol[pos] = col[e];
        pval[pos] = vals[e] * DECAY_;   // fold DECAY into edge value
    }
}

// ---------------------------------------------------------------------------
// SpMM fused with weights: cur_out[g] = sum_edges val * cur_in[col];
// then weights[g*4+l] += mean_kd(ck*cq) computed from the in-register row.
// block = 128 threads (float4 each -> 512 cols), grid = G_
// 4-edge unroll: 4 outstanding 16B loads/thread to cover L2/HBM latency.
// ---------------------------------------------------------------------------
__global__ __launch_bounds__(128) void spmm_kernel(
        const float* __restrict__ cur_in,
        float* __restrict__ cur_out,
        const int* __restrict__ offs,
        const int* __restrict__ pcol,
        const float* __restrict__ pval,
        const float* __restrict__ Wk,
        const float* __restrict__ Wq,
        float* __restrict__ weights) {
    const int g = blockIdx.x;
    const int t = threadIdx.x;
    const int c4 = t * 4;
    const int s = offs[g], e = offs[g + 1];
    float4 acc = {0.f, 0.f, 0.f, 0.f};
    int i = s;
    for (; i + 4 <= e; i += 4) {
        int col0 = pcol[i],     col1 = pcol[i + 1];
        int col2 = pcol[i + 2], col3 = pcol[i + 3];
        float v0 = pval[i],     v1 = pval[i + 1];
        float v2 = pval[i + 2], v3 = pval[i + 3];
        const float* p0 = cur_in + (size_t)col0 * LC_ + c4;
        const float* p1 = cur_in + (size_t)col1 * LC_ + c4;
        const float* p2 = cur_in + (size_t)col2 * LC_ + c4;
        const float* p3 = cur_in + (size_t)col3 * LC_ + c4;
        float4 a = *(const float4*)p0;
        float4 b = *(const float4*)p1;
        float4 c = *(const float4*)p2;
        float4 d = *(const float4*)p3;
        acc.x += v0 * a.x + v1 * b.x + v2 * c.x + v3 * d.x;
        acc.y += v0 * a.y + v1 * b.y + v2 * c.y + v3 * d.y;
        acc.z += v0 * a.z + v1 * b.z + v2 * c.z + v3 * d.z;
        acc.w += v0 * a.w + v1 * b.w + v2 * c.w + v3 * d.w;
    }
    for (; i < e; ++i) {
        int col0 = pcol[i];
        float v0 = pval[i];
        float4 a = *(const float4*)(cur_in + (size_t)col0 * LC_ + c4);
        acc.x += v0 * a.x;
        acc.y += v0 * a.y;
        acc.z += v0 * a.z;
        acc.w += v0 * a.w;
    }
    *(float4*)(cur_out + (size_t)g * LC_ + c4) = acc;

    // fused weights contribution (row is in registers)
    const int l = t >> 5;
    const int cc = (t & 31) * 4;
    float w = weight_contrib(acc, cc, Wk, Wq);
    if ((t & 31) == 0) weights[g * 4 + l] += w;
}

// ---------------------------------------------------------------------------
// final: for NG_ g's per block: acc=cur0+cur1+cur2 (LDS), v=(acc@Wv)*w, LN
// 256 threads: row-group r = t>>5 handles 8 rows; col-group cg = t&31
// ---------------------------------------------------------------------------
__global__ __launch_bounds__(256) void final_kernel(
        const float* __restrict__ cur0,
        const float* __restrict__ cur1,
        const float* __restrict__ cur2,
        const float* __restrict__ weights,
        const float* __restrict__ Wv,
        const float* __restrict__ gamma,
        const float* __restrict__ beta,
        float* __restrict__ out) {
    const int g0 = blockIdx.x * NG_;
    const int t = threadIdx.x;
    __shared__ float a[NG_ * 4][C_];   // 32 KB
    __shared__ float wsh[NG_ * 4];

    // stage summed rows: 16 g * 512 floats = 2048 float4
    {
        const float4* c0 = (const float4*)(cur0 + (size_t)g0 * LC_);
        const float4* c1 = (const float4*)(cur1 + (size_t)g0 * LC_);
        const float4* c2 = (const float4*)(cur2 + (size_t)g0 * LC_);
        float4* a4 = (float4*)a;
#pragma unroll
        for (int i = 0; i < 8; ++i) {
            int idx = i * 256 + t;
            float4 p = c0[idx], q = c1[idx], r = c2[idx];
            float4 sum = {p.x + q.x + r.x, p.y + q.y + r.y,
                          p.z + q.z + r.z, p.w + q.w + r.w};
            a4[idx] = sum;
        }
        if (t < NG_ * 4) wsh[t] = weights[g0 * 4 + t];
    }
    __syncthreads();

    const int r = t >> 5;
    const int cg = t & 31;
    float4 acc[8];
#pragma unroll
    for (int j = 0; j < 8; ++j) acc[j] = {0.f, 0.f, 0.f, 0.f};

    for (int c = 0; c < C_; c += 4) {
        float4 wv0 = *(const float4*)(Wv + (size_t)(c + 0) * C_ + cg * 4);
        float4 wv1 = *(const float4*)(Wv + (size_t)(c + 1) * C_ + cg * 4);
        float4 wv2 = *(const float4*)(Wv + (size_t)(c + 2) * C_ + cg * 4);
        float4 wv3 = *(const float4*)(Wv + (size_t)(c + 3) * C_ + cg * 4);
#pragma unroll
        for (int j = 0; j < 8; ++j) {
            float4 av = *(const float4*)(&a[r * 8 + j][c]);
            acc[j].x += av.x * wv0.x + av.y * wv1.x + av.z * wv2.x + av.w * wv3.x;
            acc[j].y += av.x * wv0.y + av.y * wv1.y + av.z * wv2.y + av.w * wv3.y;
            acc[j].z += av.x * wv0.z + av.y * wv1.z + av.z * wv2.z + av.w * wv3.z;
            acc[j].w += av.x * wv0.w + av.y * wv1.w + av.z * wv2.w + av.w * wv3.w;
        }
    }

    float4 gm = *(const float4*)(gamma + cg * 4);
    float4 bt = *(const float4*)(beta + cg * 4);

#pragma unroll
    for (int j = 0; j < 8; ++j) {
        const int rid = r * 8 + j;
        float w = wsh[rid];
        float4 v = {acc[j].x * w, acc[j].y * w, acc[j].z * w, acc[j].w * w};

        float sum = v.x + v.y + v.z + v.w;
#pragma unroll
        for (int m = 1; m < 32; m <<= 1) sum += __shfl_xor(sum, m);
        float mu = sum * (1.0f / 128.0f);
        float4 d = {v.x - mu, v.y - mu, v.z - mu, v.w - mu};
        float ss = d.x * d.x + d.y * d.y + d.z * d.z + d.w * d.w;
#pragma unroll
        for (int m = 1; m < 32; m <<= 1) ss += __shfl_xor(ss, m);
        float rs = rsqrtf(ss * (1.0f / 128.0f) + LN_EPS_);

        float4 o;
        o.x = d.x * rs * gm.x + bt.x;
        o.y = d.y * rs * gm.y + bt.y;
        o.z = d.z * rs * gm.z + bt.z;
        o.w = d.w * rs * gm.w + bt.w;

        const int g_local = rid >> 2;
        const int l = rid & 3;
        *(float4*)(out + ((size_t)l * G_ + (g0 + g_local)) * C_ + cg * 4) = o;
    }
}

// ---------------------------------------------------------------------------
extern "C" void kernel_launch(void* const* d_in, const int* in_sizes, int n_in,
                              void* d_out, int out_size, void* d_ws, size_t ws_size,
                              hipStream_t stream) {
    const float* x       = (const float*)d_in[0];
    const int*   e_row   = (const int*)d_in[1];
    const int*   e_col   = (const int*)d_in[2];
    const float* e_val   = (const float*)d_in[3];
    const float* Wk      = (const float*)d_in[4];
    const float* Wq      = (const float*)d_in[5];
    const float* Wv      = (const float*)d_in[6];
    const float* gamma   = (const float*)d_in[7];
    const float* beta    = (const float*)d_in[8];
    float* out = (float*)d_out;

    // workspace bump allocator (256B aligned)
    char* p = (char*)d_ws;
    auto alloc = [&](size_t bytes) -> void* {
        void* r = (void*)p;
        p += (bytes + 255) & ~(size_t)255;
        return r;
    };
    float* cur0    = (float*)alloc((size_t)G_ * LC_ * 4);
    float* cur1    = (float*)alloc((size_t)G_ * LC_ * 4);
    float* cur2    = (float*)alloc((size_t)G_ * LC_ * 4);
    float* weights = (float*)alloc((size_t)G_ * L_ * 4);
    int*   counts  = (int*)alloc((size_t)G_ * 4);
    int*   offsets = (int*)alloc((size_t)(G_ + 1) * 4);
    int*   cursor  = (int*)alloc((size_t)G_ * 4);
    int*   pcol    = (int*)alloc((size_t)E_ * 4);
    float* pval    = (float*)alloc((size_t)E_ * 4);

    // CSR build
    hipMemsetAsync(counts, 0, (size_t)G_ * 4, stream);
    hist_kernel<<<(E_ + 255) / 256, 256, 0, stream>>>(e_row, counts);
    scan_kernel<<<1, 1024, 0, stream>>>(counts, offsets, G_);
    hipMemcpyAsync(cursor, offsets, (size_t)G_ * 4, hipMemcpyDeviceToDevice, stream);
    scatter_kernel<<<(E_ + 255) / 256, 256, 0, stream>>>(e_row, e_col, e_val,
                                                         cursor, pcol, pval);

    // transpose + initial weights
    init_kernel<<<G_, 128, 0, stream>>>(x, Wk, Wq, cur0, weights);

    // iterations (weights fused into spmm)
    spmm_kernel<<<G_, 128, 0, stream>>>(cur0, cur1, offsets, pcol, pval,
                                        Wk, Wq, weights);
    spmm_kernel<<<G_, 128, 0, stream>>>(cur1, cur2, offsets, pcol, pval,
                                        Wk, Wq, weights);

    // values @ Wv, * weights, LayerNorm
    final_kernel<<<G_ / NG_, 256, 0, stream>>>(cur0, cur1, cur2, weights, Wv,
                                               gamma, beta, out);
}

// Round 8
// 669.838 us; speedup vs baseline: 1.3707x; 1.0177x over previous
//
#include <hip/hip_runtime.h>
#include <hip/hip_bf16.h>

// Problem constants
#define L_  4
#define G_  20000
#define C_  128
#define E_  320000
#define KD_ 16
#define LC_ 512            // L_*C_
#define DECAY_ 0.5f
#define LN_EPS_ 1e-5f
#define NG_ 16             // g's per final block (64 rows)

// ---------------------------------------------------------------------------
// Weight contribution for one l-row held by a 32-lane group as float4/lane.
// ---------------------------------------------------------------------------
__device__ __forceinline__ float weight_contrib(float4 acc, int cc,
                                                const float* __restrict__ Wk,
                                                const float* __restrict__ Wq) {
    float kp[16], qp[16];
#pragma unroll
    for (int i = 0; i < 16; ++i) { kp[i] = 0.f; qp[i] = 0.f; }
    float av[4] = {acc.x, acc.y, acc.z, acc.w};
#pragma unroll
    for (int j = 0; j < 4; ++j) {
        const float4* wkr = (const float4*)(Wk + (size_t)(cc + j) * KD_);
        const float4* wqr = (const float4*)(Wq + (size_t)(cc + j) * KD_);
        float aj = av[j];
#pragma unroll
        for (int q4 = 0; q4 < 4; ++q4) {
            float4 wk = wkr[q4], wq = wqr[q4];
            kp[q4 * 4 + 0] += aj * wk.x; kp[q4 * 4 + 1] += aj * wk.y;
            kp[q4 * 4 + 2] += aj * wk.z; kp[q4 * 4 + 3] += aj * wk.w;
            qp[q4 * 4 + 0] += aj * wq.x; qp[q4 * 4 + 1] += aj * wq.y;
            qp[q4 * 4 + 2] += aj * wq.z; qp[q4 * 4 + 3] += aj * wq.w;
        }
    }
#pragma unroll
    for (int i = 0; i < 16; ++i) {
#pragma unroll
        for (int m = 1; m < 32; m <<= 1) qp[i] += __shfl_xor(qp[i], m);
    }
    float s = 0.f;
#pragma unroll
    for (int i = 0; i < 16; ++i) s += kp[i] * qp[i];
#pragma unroll
    for (int m = 1; m < 32; m <<= 1) s += __shfl_xor(s, m);
    return s * (1.0f / 16.0f);
}

// ---------------------------------------------------------------------------
// init: cur0[g][l*128+c] = x[l][g][c]; weights[g*4+l] = mean_kd(k*q)
// ---------------------------------------------------------------------------
__global__ __launch_bounds__(128) void init_kernel(
        const float* __restrict__ x,
        const float* __restrict__ Wk,
        const float* __restrict__ Wq,
        float* __restrict__ cur0,
        float* __restrict__ weights) {
    const int g = blockIdx.x;
    const int t = threadIdx.x;
    const int l = t >> 5;
    const int cc = (t & 31) * 4;

    float4 xv = *(const float4*)(x + ((size_t)l * G_ + g) * C_ + cc);
    *(float4*)(cur0 + (size_t)g * LC_ + l * C_ + cc) = xv;

    float w = weight_contrib(xv, cc, Wk, Wq);
    if ((t & 31) == 0) weights[g * 4 + l] = w;
}

// ---------------------------------------------------------------------------
// CSR build: hist -> parallel 3-phase scan -> scatter
// ---------------------------------------------------------------------------
__global__ void hist_kernel(const int* __restrict__ row, int* __restrict__ counts) {
    int e = blockIdx.x * 256 + threadIdx.x;
    if (e < E_) atomicAdd(&counts[row[e]], 1);
}

// phase A: per-256-chunk local exclusive scan + chunk totals
__global__ __launch_bounds__(256) void scan_blocks_kernel(
        const int* __restrict__ counts, int* __restrict__ offsets,
        int* __restrict__ btot, int n) {
    const int b = blockIdx.x, t = threadIdx.x;
    const int i = b * 256 + t;
    const int lane = t & 63, wid = t >> 6;
    int v = (i < n) ? counts[i] : 0;
    int incl = v;
#pragma unroll
    for (int d = 1; d < 64; d <<= 1) {
        int o = __shfl_up(incl, d);
        if (lane >= d) incl += o;
    }
    __shared__ int ws[4];
    if (lane == 63) ws[wid] = incl;
    __syncthreads();
    int waveoff = 0;
#pragma unroll
    for (int k = 0; k < 4; ++k) if (k < wid) waveoff += ws[k];
    int excl = waveoff + incl - v;
    if (i < n) offsets[i] = excl;
    if (t == 255) btot[b] = waveoff + incl;   // block total
}

// phase B: single block scans the 79 chunk totals (in place, exclusive);
// writes grand total to offsets[n]
__global__ __launch_bounds__(128) void scan_totals_kernel(
        int* __restrict__ btot, int* __restrict__ offsets, int n, int nb) {
    const int t = threadIdx.x;
    const int lane = t & 63, wid = t >> 6;
    int v = (t < nb) ? btot[t] : 0;
    int incl = v;
#pragma unroll
    for (int d = 1; d < 64; d <<= 1) {
        int o = __shfl_up(incl, d);
        if (lane >= d) incl += o;
    }
    __shared__ int ws[2];
    if (lane == 63) ws[wid] = incl;
    __syncthreads();
    int off = (wid == 1) ? ws[0] : 0;
    int excl = off + incl - v;
    if (t < nb) btot[t] = excl;
    if (t == nb - 1) offsets[n] = excl + v;   // grand total
}

// phase C: add scanned chunk bases
__global__ __launch_bounds__(256) void add_base_kernel(
        int* __restrict__ offsets, const int* __restrict__ btot, int n) {
    int i = blockIdx.x * 256 + threadIdx.x;
    if (i < n) offsets[i] += btot[blockIdx.x];
}

__global__ void scatter_kernel(const int* __restrict__ row,
                               const int* __restrict__ col,
                               const float* __restrict__ vals,
                               int* __restrict__ cursor,
                               int* __restrict__ pcol,
                               float* __restrict__ pval) {
    int e = blockIdx.x * 256 + threadIdx.x;
    if (e < E_) {
        int r = row[e];
        int pos = atomicAdd(&cursor[r], 1);
        pcol[pos] = col[e];
        pval[pos] = vals[e] * DECAY_;   // fold DECAY into edge value
    }
}

// ---------------------------------------------------------------------------
// SpMM fused with weights. 8-edge batched pipeline: 8 independent index
// loads (1 latency round) -> 8 independent gathers (1 round) -> FMAs.
// ---------------------------------------------------------------------------
__global__ __launch_bounds__(128) void spmm_kernel(
        const float* __restrict__ cur_in,
        float* __restrict__ cur_out,
        const int* __restrict__ offs,
        const int* __restrict__ pcol,
        const float* __restrict__ pval,
        const float* __restrict__ Wk,
        const float* __restrict__ Wq,
        float* __restrict__ weights) {
    const int g = blockIdx.x;
    const int t = threadIdx.x;
    const int c4 = t * 4;
    const int s = offs[g], e = offs[g + 1];
    float4 acc = {0.f, 0.f, 0.f, 0.f};
    int i = s;

    for (; i + 8 <= e; i += 8) {
        int   col[8];
        float vv[8];
#pragma unroll
        for (int u = 0; u < 8; ++u) { col[u] = pcol[i + u]; vv[u] = pval[i + u]; }
        float4 d[8];
#pragma unroll
        for (int u = 0; u < 8; ++u)
            d[u] = *(const float4*)(cur_in + (size_t)col[u] * LC_ + c4);
#pragma unroll
        for (int u = 0; u < 8; ++u) {
            acc.x += vv[u] * d[u].x;
            acc.y += vv[u] * d[u].y;
            acc.z += vv[u] * d[u].z;
            acc.w += vv[u] * d[u].w;
        }
    }
    if (i + 4 <= e) {
        int   col[4];
        float vv[4];
#pragma unroll
        for (int u = 0; u < 4; ++u) { col[u] = pcol[i + u]; vv[u] = pval[i + u]; }
        float4 d[4];
#pragma unroll
        for (int u = 0; u < 4; ++u)
            d[u] = *(const float4*)(cur_in + (size_t)col[u] * LC_ + c4);
#pragma unroll
        for (int u = 0; u < 4; ++u) {
            acc.x += vv[u] * d[u].x;
            acc.y += vv[u] * d[u].y;
            acc.z += vv[u] * d[u].z;
            acc.w += vv[u] * d[u].w;
        }
        i += 4;
    }
    for (; i < e; ++i) {
        int col0 = pcol[i];
        float v0 = pval[i];
        float4 a = *(const float4*)(cur_in + (size_t)col0 * LC_ + c4);
        acc.x += v0 * a.x;
        acc.y += v0 * a.y;
        acc.z += v0 * a.z;
        acc.w += v0 * a.w;
    }
    *(float4*)(cur_out + (size_t)g * LC_ + c4) = acc;

    // fused weights contribution (row is in registers)
    const int l = t >> 5;
    const int cc = (t & 31) * 4;
    float w = weight_contrib(acc, cc, Wk, Wq);
    if ((t & 31) == 0) weights[g * 4 + l] += w;
}

// ---------------------------------------------------------------------------
// final: for NG_ g's per block: acc=cur0+cur1+cur2 (LDS), v=(acc@Wv)*w, LN
// ---------------------------------------------------------------------------
__global__ __launch_bounds__(256) void final_kernel(
        const float* __restrict__ cur0,
        const float* __restrict__ cur1,
        const float* __restrict__ cur2,
        const float* __restrict__ weights,
        const float* __restrict__ Wv,
        const float* __restrict__ gamma,
        const float* __restrict__ beta,
        float* __restrict__ out) {
    const int g0 = blockIdx.x * NG_;
    const int t = threadIdx.x;
    __shared__ float a[NG_ * 4][C_];   // 32 KB
    __shared__ float wsh[NG_ * 4];

    {
        const float4* c0 = (const float4*)(cur0 + (size_t)g0 * LC_);
        const float4* c1 = (const float4*)(cur1 + (size_t)g0 * LC_);
        const float4* c2 = (const float4*)(cur2 + (size_t)g0 * LC_);
        float4* a4 = (float4*)a;
#pragma unroll
        for (int i = 0; i < 8; ++i) {
            int idx = i * 256 + t;
            float4 p = c0[idx], q = c1[idx], r = c2[idx];
            float4 sum = {p.x + q.x + r.x, p.y + q.y + r.y,
                          p.z + q.z + r.z, p.w + q.w + r.w};
            a4[idx] = sum;
        }
        if (t < NG_ * 4) wsh[t] = weights[g0 * 4 + t];
    }
    __syncthreads();

    const int r = t >> 5;
    const int cg = t & 31;
    float4 acc[8];
#pragma unroll
    for (int j = 0; j < 8; ++j) acc[j] = {0.f, 0.f, 0.f, 0.f};

    for (int c = 0; c < C_; c += 4) {
        float4 wv0 = *(const float4*)(Wv + (size_t)(c + 0) * C_ + cg * 4);
        float4 wv1 = *(const float4*)(Wv + (size_t)(c + 1) * C_ + cg * 4);
        float4 wv2 = *(const float4*)(Wv + (size_t)(c + 2) * C_ + cg * 4);
        float4 wv3 = *(const float4*)(Wv + (size_t)(c + 3) * C_ + cg * 4);
#pragma unroll
        for (int j = 0; j < 8; ++j) {
            float4 av = *(const float4*)(&a[r * 8 + j][c]);
            acc[j].x += av.x * wv0.x + av.y * wv1.x + av.z * wv2.x + av.w * wv3.x;
            acc[j].y += av.x * wv0.y + av.y * wv1.y + av.z * wv2.y + av.w * wv3.y;
            acc[j].z += av.x * wv0.z + av.y * wv1.z + av.z * wv2.z + av.w * wv3.z;
            acc[j].w += av.x * wv0.w + av.y * wv1.w + av.z * wv2.w + av.w * wv3.w;
        }
    }

    float4 gm = *(const float4*)(gamma + cg * 4);
    float4 bt = *(const float4*)(beta + cg * 4);

#pragma unroll
    for (int j = 0; j < 8; ++j) {
        const int rid = r * 8 + j;
        float w = wsh[rid];
        float4 v = {acc[j].x * w, acc[j].y * w, acc[j].z * w, acc[j].w * w};

        float sum = v.x + v.y + v.z + v.w;
#pragma unroll
        for (int m = 1; m < 32; m <<= 1) sum += __shfl_xor(sum, m);
        float mu = sum * (1.0f / 128.0f);
        float4 d = {v.x - mu, v.y - mu, v.z - mu, v.w - mu};
        float ss = d.x * d.x + d.y * d.y + d.z * d.z + d.w * d.w;
#pragma unroll
        for (int m = 1; m < 32; m <<= 1) ss += __shfl_xor(ss, m);
        float rs = rsqrtf(ss * (1.0f / 128.0f) + LN_EPS_);

        float4 o;
        o.x = d.x * rs * gm.x + bt.x;
        o.y = d.y * rs * gm.y + bt.y;
        o.z = d.z * rs * gm.z + bt.z;
        o.w = d.w * rs * gm.w + bt.w;

        const int g_local = rid >> 2;
        const int l = rid & 3;
        *(float4*)(out + ((size_t)l * G_ + (g0 + g_local)) * C_ + cg * 4) = o;
    }
}

// ---------------------------------------------------------------------------
extern "C" void kernel_launch(void* const* d_in, const int* in_sizes, int n_in,
                              void* d_out, int out_size, void* d_ws, size_t ws_size,
                              hipStream_t stream) {
    const float* x       = (const float*)d_in[0];
    const int*   e_row   = (const int*)d_in[1];
    const int*   e_col   = (const int*)d_in[2];
    const float* e_val   = (const float*)d_in[3];
    const float* Wk      = (const float*)d_in[4];
    const float* Wq      = (const float*)d_in[5];
    const float* Wv      = (const float*)d_in[6];
    const float* gamma   = (const float*)d_in[7];
    const float* beta    = (const float*)d_in[8];
    float* out = (float*)d_out;

    // workspace bump allocator (256B aligned)
    char* p = (char*)d_ws;
    auto alloc = [&](size_t bytes) -> void* {
        void* r = (void*)p;
        p += (bytes + 255) & ~(size_t)255;
        return r;
    };
    float* cur0    = (float*)alloc((size_t)G_ * LC_ * 4);
    float* cur1    = (float*)alloc((size_t)G_ * LC_ * 4);
    float* cur2    = (float*)alloc((size_t)G_ * LC_ * 4);
    float* weights = (float*)alloc((size_t)G_ * L_ * 4);
    int*   counts  = (int*)alloc((size_t)G_ * 4);
    int*   offsets = (int*)alloc((size_t)(G_ + 1) * 4);
    int*   cursor  = (int*)alloc((size_t)G_ * 4);
    int*   pcol    = (int*)alloc((size_t)E_ * 4);
    float* pval    = (float*)alloc((size_t)E_ * 4);
    const int NB   = (G_ + 255) / 256;           // 79 scan chunks
    int*   btot    = (int*)alloc((size_t)NB * 4);

    // CSR build
    hipMemsetAsync(counts, 0, (size_t)G_ * 4, stream);
    hist_kernel<<<(E_ + 255) / 256, 256, 0, stream>>>(e_row, counts);
    scan_blocks_kernel<<<NB, 256, 0, stream>>>(counts, offsets, btot, G_);
    scan_totals_kernel<<<1, 128, 0, stream>>>(btot, offsets, G_, NB);
    add_base_kernel<<<NB, 256, 0, stream>>>(offsets, btot, G_);
    hipMemcpyAsync(cursor, offsets, (size_t)G_ * 4, hipMemcpyDeviceToDevice, stream);
    scatter_kernel<<<(E_ + 255) / 256, 256, 0, stream>>>(e_row, e_col, e_val,
                                                         cursor, pcol, pval);

    // transpose + initial weights
    init_kernel<<<G_, 128, 0, stream>>>(x, Wk, Wq, cur0, weights);

    // iterations (weights fused into spmm)
    spmm_kernel<<<G_, 128, 0, stream>>>(cur0, cur1, offsets, pcol, pval,
                                        Wk, Wq, weights);
    spmm_kernel<<<G_, 128, 0, stream>>>(cur1, cur2, offsets, pcol, pval,
                                        Wk, Wq, weights);

    // values @ Wv, * weights, LayerNorm
    final_kernel<<<G_ / NG_, 256, 0, stream>>>(cur0, cur1, cur2, weights, Wv,
                                               gamma, beta, out);
}

// Round 11
// 369.478 us; speedup vs baseline: 2.4850x; 1.8129x over previous
//
#include <hip/hip_runtime.h>
#include <hip/hip_bf16.h>

// Problem constants
#define L_  4
#define G_  20000
#define C_  128
#define E_  320000
#define KD_ 16
#define LC_ 512            // L_*C_
#define DECAY_ 0.5f
#define LN_EPS_ 1e-5f
#define NG_ 16             // g's per final block (64 rows)

// bf16 helpers: cur rows stored as 64 x uint4 (8 bf16 per uint4, 1KB/row)
__device__ __forceinline__ float bflo(unsigned u) { return __uint_as_float(u << 16); }
__device__ __forceinline__ float bfhi(unsigned u) { return __uint_as_float(u & 0xFFFF0000u); }
__device__ __forceinline__ unsigned pack_bf2(float a, float b) {
    __hip_bfloat16 ha = __float2bfloat16(a), hb = __float2bfloat16(b);
    unsigned short ua = *reinterpret_cast<unsigned short*>(&ha);
    unsigned short ub = *reinterpret_cast<unsigned short*>(&hb);
    return (unsigned)ua | ((unsigned)ub << 16);
}

// ---------------------------------------------------------------------------
// init: cur0[g] = bf16(x); kq0[g] = [K0(64) | Q0(64)] f32 (K[l*16+kd]);
// weights[g*4+l] = mean_kd(K0*Q0).  Block = 64 threads, one g.
// Weights path is kept in f32 end-to-end: LN cancels |w|, so w needs
// ABSOLUTE accuracy ~1e-4 (bf16-infected w caused R10's 4.95 absmax).
// ---------------------------------------------------------------------------
__global__ __launch_bounds__(64) void init_kernel(
        const float* __restrict__ x,
        const float* __restrict__ Wk,
        const float* __restrict__ Wq,
        uint4* __restrict__ cur0,
        float* __restrict__ kq0,
        float* __restrict__ weights) {
    const int g = blockIdx.x;
    const int t = threadIdx.x;
    const int l = t >> 4;
    const int ch = (t & 15) * 8;

    __shared__ float xs[4][132];   // +4 pad: banks (4l+c)&31 -> conflict-free

    const float4* xr = (const float4*)(x + ((size_t)l * G_ + g) * C_ + ch);
    float4 xa = xr[0], xb = xr[1];
    *(float4*)&xs[l][ch]     = xa;
    *(float4*)&xs[l][ch + 4] = xb;

    uint4 o;
    o.x = pack_bf2(xa.x, xa.y);
    o.y = pack_bf2(xa.z, xa.w);
    o.z = pack_bf2(xb.x, xb.y);
    o.w = pack_bf2(xb.z, xb.w);
    cur0[(size_t)g * 64 + t] = o;
    __syncthreads();

    // projection: lane t -> (l = t>>4, kd = t&15)
    const int kd = t & 15;
    const float* xrow = xs[l];
    float K = 0.f, Q = 0.f;
#pragma unroll 8
    for (int c = 0; c < C_; ++c) {
        float xv = xrow[c];
        K += xv * Wk[c * KD_ + kd];
        Q += xv * Wq[c * KD_ + kd];
    }
    kq0[(size_t)g * 128 + t]      = K;
    kq0[(size_t)g * 128 + 64 + t] = Q;

    float prod = K * Q;
#pragma unroll
    for (int m = 1; m < 16; m <<= 1) prod += __shfl_xor(prod, m);
    if ((t & 15) == 0) weights[g * 4 + l] = prod * (1.0f / 16.0f);
}

// ---------------------------------------------------------------------------
// CSR build: hist -> parallel 3-phase scan -> scatter
// ---------------------------------------------------------------------------
__global__ void hist_kernel(const int* __restrict__ row, int* __restrict__ counts) {
    int e = blockIdx.x * 256 + threadIdx.x;
    if (e < E_) atomicAdd(&counts[row[e]], 1);
}

__global__ __launch_bounds__(256) void scan_blocks_kernel(
        const int* __restrict__ counts, int* __restrict__ offsets,
        int* __restrict__ btot, int n) {
    const int b = blockIdx.x, t = threadIdx.x;
    const int i = b * 256 + t;
    const int lane = t & 63, wid = t >> 6;
    int v = (i < n) ? counts[i] : 0;
    int incl = v;
#pragma unroll
    for (int d = 1; d < 64; d <<= 1) {
        int o = __shfl_up(incl, d);
        if (lane >= d) incl += o;
    }
    __shared__ int ws[4];
    if (lane == 63) ws[wid] = incl;
    __syncthreads();
    int waveoff = 0;
#pragma unroll
    for (int k = 0; k < 4; ++k) if (k < wid) waveoff += ws[k];
    int excl = waveoff + incl - v;
    if (i < n) offsets[i] = excl;
    if (t == 255) btot[b] = waveoff + incl;
}

__global__ __launch_bounds__(128) void scan_totals_kernel(
        int* __restrict__ btot, int* __restrict__ offsets, int n, int nb) {
    const int t = threadIdx.x;
    const int lane = t & 63, wid = t >> 6;
    int v = (t < nb) ? btot[t] : 0;
    int incl = v;
#pragma unroll
    for (int d = 1; d < 64; d <<= 1) {
        int o = __shfl_up(incl, d);
        if (lane >= d) incl += o;
    }
    __shared__ int ws[2];
    if (lane == 63) ws[wid] = incl;
    __syncthreads();
    int off = (wid == 1) ? ws[0] : 0;
    int excl = off + incl - v;
    if (t < nb) btot[t] = excl;
    if (t == nb - 1) offsets[n] = excl + v;
}

__global__ __launch_bounds__(256) void add_base_kernel(
        int* __restrict__ offsets, const int* __restrict__ btot, int n) {
    int i = blockIdx.x * 256 + threadIdx.x;
    if (i < n) offsets[i] += btot[blockIdx.x];
}

__global__ void scatter_kernel(const int* __restrict__ row,
                               const int* __restrict__ col,
                               const float* __restrict__ vals,
                               int* __restrict__ cursor,
                               int* __restrict__ pcol,
                               float* __restrict__ pval) {
    int e = blockIdx.x * 256 + threadIdx.x;
    if (e < E_) {
        int r = row[e];
        int pos = atomicAdd(&cursor[r], 1);
        pcol[pos] = col[e];
        pval[pos] = vals[e] * DECAY_;   // fold DECAY into edge value
    }
}

// ---------------------------------------------------------------------------
// Combined SpMM: per edge gather 1KB bf16 cur row (values path) + 512B f32
// kq row (weights path). Weights from the f32 kq chain only — projection
// commutes with SpMM: (S cur) @ Wk = S (cur @ Wk).
// Block = 64 threads; lane t: uint4 of cur + float2 of kq.
// ---------------------------------------------------------------------------
__global__ __launch_bounds__(64) void spmm_kernel(
        const uint4* __restrict__ cur_in,
        uint4* __restrict__ cur_out,
        const float2* __restrict__ kq_in,
        float2* __restrict__ kq_out,
        const int* __restrict__ offs,
        const int* __restrict__ pcol,
        const float* __restrict__ pval,
        float* __restrict__ weights) {
    const int g = blockIdx.x;
    const int t = threadIdx.x;
    const int s = offs[g], e = offs[g + 1];
    float acc[8];
#pragma unroll
    for (int j = 0; j < 8; ++j) acc[j] = 0.f;
    float2 ka = {0.f, 0.f};
    int i = s;

    for (; i + 4 <= e; i += 4) {
        int   col[4];
        float vv[4];
#pragma unroll
        for (int u = 0; u < 4; ++u) { col[u] = pcol[i + u]; vv[u] = pval[i + u]; }
        uint4  d[4];
        float2 p[4];
#pragma unroll
        for (int u = 0; u < 4; ++u) d[u] = cur_in[(size_t)col[u] * 64 + t];
#pragma unroll
        for (int u = 0; u < 4; ++u) p[u] = kq_in[(size_t)col[u] * 64 + t];
#pragma unroll
        for (int u = 0; u < 4; ++u) {
            acc[0] += vv[u] * bflo(d[u].x); acc[1] += vv[u] * bfhi(d[u].x);
            acc[2] += vv[u] * bflo(d[u].y); acc[3] += vv[u] * bfhi(d[u].y);
            acc[4] += vv[u] * bflo(d[u].z); acc[5] += vv[u] * bfhi(d[u].z);
            acc[6] += vv[u] * bflo(d[u].w); acc[7] += vv[u] * bfhi(d[u].w);
            ka.x   += vv[u] * p[u].x;
            ka.y   += vv[u] * p[u].y;
        }
    }
    for (; i < e; ++i) {
        int c0 = pcol[i];
        float v0 = pval[i];
        uint4 d = cur_in[(size_t)c0 * 64 + t];
        float2 p = kq_in[(size_t)c0 * 64 + t];
        acc[0] += v0 * bflo(d.x); acc[1] += v0 * bfhi(d.x);
        acc[2] += v0 * bflo(d.y); acc[3] += v0 * bfhi(d.y);
        acc[4] += v0 * bflo(d.z); acc[5] += v0 * bfhi(d.z);
        acc[6] += v0 * bflo(d.w); acc[7] += v0 * bfhi(d.w);
        ka.x   += v0 * p.x;
        ka.y   += v0 * p.y;
    }

    uint4 o;
    o.x = pack_bf2(acc[0], acc[1]);
    o.y = pack_bf2(acc[2], acc[3]);
    o.z = pack_bf2(acc[4], acc[5]);
    o.w = pack_bf2(acc[6], acc[7]);
    cur_out[(size_t)g * 64 + t] = o;
    kq_out[(size_t)g * 64 + t] = ka;

    // weights: lanes t<32 hold K[l][kd pair] (l=t>>3), lane t+32 holds the
    // matching Q pair. prod reduced over the 8-lane l-group (16 kd total).
    float px = __shfl_xor(ka.x, 32);
    float py = __shfl_xor(ka.y, 32);
    float prod = ka.x * px + ka.y * py;
#pragma unroll
    for (int m = 1; m < 8; m <<= 1) prod += __shfl_xor(prod, m);
    if (t < 32 && (t & 7) == 0) weights[g * 4 + (t >> 3)] += prod * (1.0f / 16.0f);
}

// ---------------------------------------------------------------------------
// final: x_acc = x(f32) + cur1(bf16) + cur2(bf16) staged to LDS;
// v = (x_acc @ Wv) * w; LayerNorm; out. 256 threads, NG_ g's per block.
// ---------------------------------------------------------------------------
__global__ __launch_bounds__(256) void final_kernel(
        const float* __restrict__ x,
        const uint4* __restrict__ cur1,
        const uint4* __restrict__ cur2,
        const float* __restrict__ weights,
        const float* __restrict__ Wv,
        const float* __restrict__ gamma,
        const float* __restrict__ beta,
        float* __restrict__ out) {
    const int g0 = blockIdx.x * NG_;
    const int t = threadIdx.x;
    __shared__ float a[NG_ * 4][C_];   // 32 KB
    __shared__ float wsh[NG_ * 4];

    // stage 64 rows x 128 ch: 1024 uint4-sized chunks (8 ch each)
#pragma unroll
    for (int i = 0; i < 4; ++i) {
        int uidx = i * 256 + t;            // 0..1023
        int rid  = uidx >> 4;              // row 0..63 (g_local*4 + l)
        int u16  = uidx & 15;              // 8-ch chunk within row
        int gl = rid >> 2, l = rid & 3;
        const float4* xr = (const float4*)(x + ((size_t)l * G_ + (g0 + gl)) * C_ + u16 * 8);
        float4 xa = xr[0], xb = xr[1];
        size_t ci = ((size_t)g0 * 4 + rid) * 16 + u16;
        uint4 c1 = cur1[ci], c2 = cur2[ci];
        float4 s0, s1;
        s0.x = xa.x + bflo(c1.x) + bflo(c2.x);
        s0.y = xa.y + bfhi(c1.x) + bfhi(c2.x);
        s0.z = xa.z + bflo(c1.y) + bflo(c2.y);
        s0.w = xa.w + bfhi(c1.y) + bfhi(c2.y);
        s1.x = xb.x + bflo(c1.z) + bflo(c2.z);
        s1.y = xb.y + bfhi(c1.z) + bfhi(c2.z);
        s1.z = xb.z + bflo(c1.w) + bflo(c2.w);
        s1.w = xb.w + bfhi(c1.w) + bfhi(c2.w);
        float4* ap = (float4*)(&a[rid][u16 * 8]);
        ap[0] = s0;
        ap[1] = s1;
    }
    if (t < NG_ * 4) wsh[t] = weights[g0 * 4 + t];
    __syncthreads();

    const int r = t >> 5;
    const int cg = t & 31;
    float4 acc[8];
#pragma unroll
    for (int j = 0; j < 8; ++j) acc[j] = {0.f, 0.f, 0.f, 0.f};

    for (int c = 0; c < C_; c += 4) {
        float4 wv0 = *(const float4*)(Wv + (size_t)(c + 0) * C_ + cg * 4);
        float4 wv1 = *(const float4*)(Wv + (size_t)(c + 1) * C_ + cg * 4);
        float4 wv2 = *(const float4*)(Wv + (size_t)(c + 2) * C_ + cg * 4);
        float4 wv3 = *(const float4*)(Wv + (size_t)(c + 3) * C_ + cg * 4);
#pragma unroll
        for (int j = 0; j < 8; ++j) {
            float4 av = *(const float4*)(&a[r * 8 + j][c]);
            acc[j].x += av.x * wv0.x + av.y * wv1.x + av.z * wv2.x + av.w * wv3.x;
            acc[j].y += av.x * wv0.y + av.y * wv1.y + av.z * wv2.y + av.w * wv3.y;
            acc[j].z += av.x * wv0.z + av.y * wv1.z + av.z * wv2.z + av.w * wv3.z;
            acc[j].w += av.x * wv0.w + av.y * wv1.w + av.z * wv2.w + av.w * wv3.w;
        }
    }

    float4 gm = *(const float4*)(gamma + cg * 4);
    float4 bt = *(const float4*)(beta + cg * 4);

#pragma unroll
    for (int j = 0; j < 8; ++j) {
        const int rid = r * 8 + j;
        float w = wsh[rid];
        float4 v = {acc[j].x * w, acc[j].y * w, acc[j].z * w, acc[j].w * w};

        float sum = v.x + v.y + v.z + v.w;
#pragma unroll
        for (int m = 1; m < 32; m <<= 1) sum += __shfl_xor(sum, m);
        float mu = sum * (1.0f / 128.0f);
        float4 d = {v.x - mu, v.y - mu, v.z - mu, v.w - mu};
        float ss = d.x * d.x + d.y * d.y + d.z * d.z + d.w * d.w;
#pragma unroll
        for (int m = 1; m < 32; m <<= 1) ss += __shfl_xor(ss, m);
        float rs = rsqrtf(ss * (1.0f / 128.0f) + LN_EPS_);

        float4 o;
        o.x = d.x * rs * gm.x + bt.x;
        o.y = d.y * rs * gm.y + bt.y;
        o.z = d.z * rs * gm.z + bt.z;
        o.w = d.w * rs * gm.w + bt.w;

        const int g_local = rid >> 2;
        const int l = rid & 3;
        *(float4*)(out + ((size_t)l * G_ + (g0 + g_local)) * C_ + cg * 4) = o;
    }
}

// ---------------------------------------------------------------------------
extern "C" void kernel_launch(void* const* d_in, const int* in_sizes, int n_in,
                              void* d_out, int out_size, void* d_ws, size_t ws_size,
                              hipStream_t stream) {
    const float* x       = (const float*)d_in[0];
    const int*   e_row   = (const int*)d_in[1];
    const int*   e_col   = (const int*)d_in[2];
    const float* e_val   = (const float*)d_in[3];
    const float* Wk      = (const float*)d_in[4];
    const float* Wq      = (const float*)d_in[5];
    const float* Wv      = (const float*)d_in[6];
    const float* gamma   = (const float*)d_in[7];
    const float* beta    = (const float*)d_in[8];
    float* out = (float*)d_out;

    // workspace bump allocator (256B aligned)
    char* p = (char*)d_ws;
    auto alloc = [&](size_t bytes) -> void* {
        void* r = (void*)p;
        p += (bytes + 255) & ~(size_t)255;
        return r;
    };
    uint4*  cur0    = (uint4*)alloc((size_t)G_ * LC_ * 2);   // bf16 rows (values)
    uint4*  cur1    = (uint4*)alloc((size_t)G_ * LC_ * 2);
    uint4*  cur2    = (uint4*)alloc((size_t)G_ * LC_ * 2);
    float*  kq0     = (float*)alloc((size_t)G_ * 128 * 4);   // f32 K|Q (weights)
    float*  kq1     = (float*)alloc((size_t)G_ * 128 * 4);
    float*  kq2     = (float*)alloc((size_t)G_ * 128 * 4);
    float*  weights = (float*)alloc((size_t)G_ * L_ * 4);
    int*    counts  = (int*)alloc((size_t)G_ * 4);
    int*    offsets = (int*)alloc((size_t)(G_ + 1) * 4);
    int*    cursor  = (int*)alloc((size_t)G_ * 4);
    int*    pcol    = (int*)alloc((size_t)E_ * 4);
    float*  pval    = (float*)alloc((size_t)E_ * 4);
    const int NB    = (G_ + 255) / 256;
    int*    btot    = (int*)alloc((size_t)NB * 4);

    // CSR build
    hipMemsetAsync(counts, 0, (size_t)G_ * 4, stream);
    hist_kernel<<<(E_ + 255) / 256, 256, 0, stream>>>(e_row, counts);
    scan_blocks_kernel<<<NB, 256, 0, stream>>>(counts, offsets, btot, G_);
    scan_totals_kernel<<<1, 128, 0, stream>>>(btot, offsets, G_, NB);
    add_base_kernel<<<NB, 256, 0, stream>>>(offsets, btot, G_);
    hipMemcpyAsync(cursor, offsets, (size_t)G_ * 4, hipMemcpyDeviceToDevice, stream);
    scatter_kernel<<<(E_ + 255) / 256, 256, 0, stream>>>(e_row, e_col, e_val,
                                                         cursor, pcol, pval);

    // transpose + bf16 cur0 + f32 K0/Q0 + weights0
    init_kernel<<<G_, 64, 0, stream>>>(x, Wk, Wq, cur0, kq0, weights);

    // iterations: bf16 values SpMM + f32 projected weights SpMM, fused
    spmm_kernel<<<G_, 64, 0, stream>>>(cur0, cur1, (const float2*)kq0,
                                       (float2*)kq1, offsets, pcol, pval, weights);
    spmm_kernel<<<G_, 64, 0, stream>>>(cur1, cur2, (const float2*)kq1,
                                       (float2*)kq2, offsets, pcol, pval, weights);

    // x_acc = x + cur1 + cur2; values @ Wv; LayerNorm
    final_kernel<<<G_ / NG_, 256, 0, stream>>>(x, cur1, cur2, weights, Wv,
                                               gamma, beta, out);
}